// Round 1
// baseline (55.367 us; speedup 1.0000x reference)
//
#include <hip/hip_runtime.h>

// EdgeNetwork: messages[e,i] = sum_j relu(edges[e,:] @ W[:, i*32+j] + b[i*32+j]) * states[e,j]
// M = 16*4096 = 65536 edge rows, F=16, D=32.
//
// Strategy: bf16 MFMA 32x32x16 (K=16 == F exactly). Per 32-edge tile, 32 MFMAs
// (one per output index n). Swapped operands: D[j][e] = sum_f W[f][n*32+j]*edges[e][f]
// so each lane owns one edge (col=lane&31) and 16 j-values in regs
// (row=(reg&3)+8*(reg>>2)+4*(lane>>5)) -> relu*state reduce is in-register + 1 shfl_xor(32).
// W pre-arranged in LDS in A-fragment order: one ds_read_b128 per fragment.

#define THREADS 512
#define WAVES_PER_BLOCK 8
#define TILES_PER_BLOCK WAVES_PER_BLOCK
#define NBLOCKS 256   // 256 blocks * 8 waves * 32 edges = 65536 rows exactly

typedef __attribute__((ext_vector_type(8))) short short8;
typedef __attribute__((ext_vector_type(16))) float f32x16;

__device__ __forceinline__ unsigned short f2bf(float x) {
    union { float f; unsigned u; } v; v.f = x;
    unsigned r = (v.u + 0x7FFFu + ((v.u >> 16) & 1u)) >> 16;  // RNE
    return (unsigned short)r;
}

__global__ __launch_bounds__(THREADS, 2)
void edgenet_kernel(const float* __restrict__ states,
                    const float* __restrict__ edges,
                    const float* __restrict__ W,
                    const float* __restrict__ bias,
                    float* __restrict__ out)
{
    // Wlds[n][lane][t] : A-fragment order for MFMA n.
    // lane l, t: A[row=l&31][k=(l>>5)*8+t] = W[f=(l>>5)*8+t][n*32 + (l&31)]
    __shared__ unsigned short Wlds[32 * 64 * 8];   // 32 KB
    // Blds[n*32 + h*16 + r] = bias[n*32 + (r&3) + 8*(r>>2) + 4*h]  (C-operand init)
    __shared__ float Blds[1024];                   // 4 KB

    const int tid  = threadIdx.x;
    const int wave = tid >> 6;
    const int lane = tid & 63;
    const int ecol = lane & 31;   // edge within tile (MFMA D column)
    const int h    = lane >> 5;   // half-wave

    const int tile = blockIdx.x * TILES_PER_BLOCK + wave;
    const long long row = (long long)tile * 32 + ecol;

    // ---- prefetch this wave's edges + states (hide HBM latency under W staging) ----
    const float* ep = edges + row * 16 + h * 8;          // 8 contiguous f-features
    const float4 ev0 = *reinterpret_cast<const float4*>(ep);
    const float4 ev1 = *reinterpret_cast<const float4*>(ep + 4);

    const float* sp = states + row * 32 + h * 4;         // j = g*8 + h*4 + (0..3)
    const float4 sv0 = *reinterpret_cast<const float4*>(sp);
    const float4 sv1 = *reinterpret_cast<const float4*>(sp + 8);
    const float4 sv2 = *reinterpret_cast<const float4*>(sp + 16);
    const float4 sv3 = *reinterpret_cast<const float4*>(sp + 24);

    // ---- stage W (bf16, A-fragment layout) and bias into LDS ----
    #pragma unroll
    for (int it = 0; it < 32; ++it) {
        int m = it * THREADS + tid;        // 0..16383, coalesced over W
        int f = m >> 10;
        int c = m & 1023;
        int n = c >> 5;
        int j = c & 31;
        int l2 = j + ((f >> 3) << 5);
        int t = f & 7;
        Wlds[((n << 6) + l2) * 8 + t] = f2bf(W[m]);
    }
    #pragma unroll
    for (int it = 0; it < 2; ++it) {
        int idx = it * THREADS + tid;      // 0..1023
        int r  = idx & 15;
        int hh = (idx >> 4) & 1;
        int n  = idx >> 5;
        Blds[idx] = bias[n * 32 + (r & 3) + ((r >> 2) << 3) + (hh << 2)];
    }
    __syncthreads();

    // ---- B fragment: B[k=(l>>5)*8+t][col=l&31] = edges[row][h*8+t] ----
    const float ef[8] = {ev0.x, ev0.y, ev0.z, ev0.w, ev1.x, ev1.y, ev1.z, ev1.w};
    short8 bfrag;
    #pragma unroll
    for (int t = 0; t < 8; ++t) bfrag[t] = (short)f2bf(ef[t]);

    // states aligned with acc reg r: s[r] = states[row][ (r>>2)*8 + h*4 + (r&3) ]
    const float s[16] = {sv0.x, sv0.y, sv0.z, sv0.w,
                         sv1.x, sv1.y, sv1.z, sv1.w,
                         sv2.x, sv2.y, sv2.z, sv2.w,
                         sv3.x, sv3.y, sv3.z, sv3.w};

    const unsigned short* wbase = &Wlds[lane * 8];
    const float* bb = &Blds[h * 16];

    float msg[32];
    #pragma unroll
    for (int n = 0; n < 32; ++n) {
        short8 afrag = *reinterpret_cast<const short8*>(wbase + n * 512);
        f32x16 acc;
        const float4 c0 = *reinterpret_cast<const float4*>(bb + n * 32);
        const float4 c1 = *reinterpret_cast<const float4*>(bb + n * 32 + 4);
        const float4 c2 = *reinterpret_cast<const float4*>(bb + n * 32 + 8);
        const float4 c3 = *reinterpret_cast<const float4*>(bb + n * 32 + 12);
        acc[0]=c0.x; acc[1]=c0.y; acc[2]=c0.z; acc[3]=c0.w;
        acc[4]=c1.x; acc[5]=c1.y; acc[6]=c1.z; acc[7]=c1.w;
        acc[8]=c2.x; acc[9]=c2.y; acc[10]=c2.z; acc[11]=c2.w;
        acc[12]=c3.x; acc[13]=c3.y; acc[14]=c3.z; acc[15]=c3.w;

        acc = __builtin_amdgcn_mfma_f32_32x32x16_bf16(afrag, bfrag, acc, 0, 0, 0);

        // messages[e][n] partial: sum over this lane's 16 j-values
        float p0 = 0.f, p1 = 0.f, p2 = 0.f, p3 = 0.f;
        #pragma unroll
        for (int r = 0; r < 16; r += 4) {
            p0 = fmaf(fmaxf(acc[r+0], 0.f), s[r+0], p0);
            p1 = fmaf(fmaxf(acc[r+1], 0.f), s[r+1], p1);
            p2 = fmaf(fmaxf(acc[r+2], 0.f), s[r+2], p2);
            p3 = fmaf(fmaxf(acc[r+3], 0.f), s[r+3], p3);
        }
        float p = (p0 + p1) + (p2 + p3);
        p += __shfl_xor(p, 32);            // combine the two half-wave j-sets
        msg[n] = p;                        // fully unrolled -> stays in VGPRs
    }

    // ---- store: lane covers (row, half h): 16 consecutive floats ----
    float* op = out + row * 32 + h * 16;
    if (h == 0) {
        *reinterpret_cast<float4*>(op +  0) = make_float4(msg[0],  msg[1],  msg[2],  msg[3]);
        *reinterpret_cast<float4*>(op +  4) = make_float4(msg[4],  msg[5],  msg[6],  msg[7]);
        *reinterpret_cast<float4*>(op +  8) = make_float4(msg[8],  msg[9],  msg[10], msg[11]);
        *reinterpret_cast<float4*>(op + 12) = make_float4(msg[12], msg[13], msg[14], msg[15]);
    } else {
        *reinterpret_cast<float4*>(op +  0) = make_float4(msg[16], msg[17], msg[18], msg[19]);
        *reinterpret_cast<float4*>(op +  4) = make_float4(msg[20], msg[21], msg[22], msg[23]);
        *reinterpret_cast<float4*>(op +  8) = make_float4(msg[24], msg[25], msg[26], msg[27]);
        *reinterpret_cast<float4*>(op + 12) = make_float4(msg[28], msg[29], msg[30], msg[31]);
    }
}

extern "C" void kernel_launch(void* const* d_in, const int* in_sizes, int n_in,
                              void* d_out, int out_size, void* d_ws, size_t ws_size,
                              hipStream_t stream) {
    (void)in_sizes; (void)n_in; (void)d_ws; (void)ws_size; (void)out_size;
    const float* states = (const float*)d_in[0];
    const float* edges  = (const float*)d_in[1];
    const float* W      = (const float*)d_in[2];
    const float* bias   = (const float*)d_in[3];
    float* out          = (float*)d_out;

    hipLaunchKernelGGL(edgenet_kernel, dim3(NBLOCKS), dim3(THREADS), 0, stream,
                       states, edges, W, bias, out);
}